// Round 14
// baseline (178.661 us; speedup 1.0000x reference)
//
#include <hip/hip_runtime.h>
#include <math.h>

#define IN_DIM 512
#define OUT_DIM 128
#define BM 64
#define BK 64
#define NKT (IN_DIM / BK)  // 8

typedef __attribute__((ext_vector_type(8))) __bf16 bf16x8;
typedef __attribute__((ext_vector_type(4))) float f32x4;
typedef __attribute__((ext_vector_type(2))) float f32x2;

// Manual RNE fp32->bf16 (bit ops). r6 lesson: native casts in the staging
// path wreck register allocation; keep the bit-op version.
__device__ inline unsigned short f2bf(float f) {
    unsigned u = __float_as_uint(f);
    u += 0x7FFFu + ((u >> 16) & 1u);  // round-to-nearest-even
    return (unsigned short)(u >> 16);
}
__device__ inline unsigned pack2f(float a, float b) {
    return (unsigned)f2bf(a) | ((unsigned)f2bf(b) << 16);
}

// XOR-swizzled byte offset within a [rows][64-bf16] LDS tile (128 B per row).
__device__ inline int swz(int row, int kbyte) {
    return row * 128 + (kbyte ^ ((row & 7) << 4));
}

// w [512][128] f32 -> wt2 k-interleaved bf16: wt2[(k>>3)*128 + n][k&7]
__global__ void wt2_kernel(const float* __restrict__ w, unsigned short* __restrict__ wt2) {
    int idx = blockIdx.x * 256 + threadIdx.x;  // 65536 total
    int k = idx >> 7;
    int n = idx & 127;
    wt2[(((k >> 3) * 128) + n) * 8 + (k & 7)] = f2bf(w[idx]);
}

// ---------------------------------------------------------------------------
// z_bf[M,128](bf16) = x[M,512] @ w[512,128] via bf16 MFMA, fp32 accumulate.
// MAX-TLP variant: 512-thread blocks, 8 waves of 16x64 output each
// (acc = 16 VGPR), LDS 8 KB/block, __launch_bounds__(512,8) caps VGPR at 64
// -> 4 blocks/CU x 8 waves = 32 waves/CU (occupancy 100%, 2x all prior
// variants). r5-proven staging: fp32 x loaded to regs (1-deep prefetch),
// bit-op packed to bf16, stored swizzled to single-buffer LDS, 2 barriers
// per K-tile. B fragments direct from L2-resident wt2. Swapped-operand MFMA
// -> packed uint2 epilogue (8-B stores).
// ---------------------------------------------------------------------------
__global__ __launch_bounds__(512, 8) void gemm_mfma(const float* __restrict__ x,
                                                    const unsigned short* __restrict__ wt2,
                                                    unsigned short* __restrict__ zb,
                                                    int M) {
    __shared__ unsigned short sA[BM * BK];  // 8 KB bf16, swizzled
    char* const pA = (char*)sA;

    const int tid  = threadIdx.x;
    const int lane = tid & 63;
    const int wid  = tid >> 6;  // 0..7
    const int wm   = wid >> 1;  // 0..3 : row quarter (16 rows)
    const int wn   = wid & 1;   // 0..1 : col half (64 cols)
    const int block_row = blockIdx.x * BM;

    const int fr  = lane & 15;  // fragment row (A=m) / col (B=n)
    const int fk4 = lane >> 4;  // k-octet group 0..3
    const int fkb = fk4 * 16;   // k byte offset in LDS row

    f32x4 acc[4];
#pragma unroll
    for (int j = 0; j < 4; ++j) acc[j] = (f32x4){0.f, 0.f, 0.f, 0.f};

    // A staging: thread t -> row t>>3 (0..63), fp32 cols (t&7)*8 .. +8
    const int a_row = tid >> 3;
    const int a_col = (tid & 7) * 8;
    const bool a_ok = (block_row + a_row) < M;
    const float* xp = x + (size_t)(block_row + a_row) * IN_DIM + a_col;
    const int a_b = swz(a_row, a_col * 2);  // 16-B store slot

    // B per-lane base in wt2 (element units)
    const unsigned short* pb = wt2 + fk4 * 1024 + (wn * 64 + fr) * 8;

    float4 ra0, ra1;
    const float4 z4 = make_float4(0.f, 0.f, 0.f, 0.f);

    // prologue: load x tile 0
    ra0 = a_ok ? *(const float4*)(xp + 0) : z4;
    ra1 = a_ok ? *(const float4*)(xp + 4) : z4;

#pragma unroll
    for (int kt = 0; kt < NKT; ++kt) {
        if (kt) __syncthreads();
        // bit-op pack fp32 -> bf16, 16-B store to swizzled LDS
        uint4 u;
        u.x = pack2f(ra0.x, ra0.y);
        u.y = pack2f(ra0.z, ra0.w);
        u.z = pack2f(ra1.x, ra1.y);
        u.w = pack2f(ra1.z, ra1.w);
        *(uint4*)(pA + a_b) = u;
        __syncthreads();

        // prefetch next x tile (overlaps with MFMA below)
        if (kt + 1 < NKT) {
            const int k0 = (kt + 1) * BK;
            ra0 = a_ok ? *(const float4*)(xp + k0 + 0) : z4;
            ra1 = a_ok ? *(const float4*)(xp + k0 + 4) : z4;
        }

        // MFMA phase: A from LDS, B from L2-resident wt2; swapped operands
#pragma unroll
        for (int ks = 0; ks < 2; ++ks) {
            const bf16x8 af = *(const bf16x8*)(pA + swz(wm * 16 + fr, ks * 64 + fkb));
            const bf16x8 bv0 = *(const bf16x8*)(pb + kt * 8192 + ks * 4096 + 0);
            const bf16x8 bv1 = *(const bf16x8*)(pb + kt * 8192 + ks * 4096 + 128);
            const bf16x8 bv2 = *(const bf16x8*)(pb + kt * 8192 + ks * 4096 + 256);
            const bf16x8 bv3 = *(const bf16x8*)(pb + kt * 8192 + ks * 4096 + 384);
            acc[0] = __builtin_amdgcn_mfma_f32_16x16x32_bf16(bv0, af, acc[0], 0, 0, 0);
            acc[1] = __builtin_amdgcn_mfma_f32_16x16x32_bf16(bv1, af, acc[1], 0, 0, 0);
            acc[2] = __builtin_amdgcn_mfma_f32_16x16x32_bf16(bv2, af, acc[2], 0, 0, 0);
            acc[3] = __builtin_amdgcn_mfma_f32_16x16x32_bf16(bv3, af, acc[3], 0, 0, 0);
        }
    }

    // Swapped C/D layout: col=lane&15 -> m, row=(lane>>4)*4+reg -> n.
    // Lane holds 4 consecutive n for fixed m: one packed 8-B store per frag.
    const int cm  = lane & 15;        // m within fragment
    const int cn0 = (lane >> 4) * 4;  // first n of the 4
    const int grow = block_row + wm * 16 + cm;
    if (grow < M) {
        unsigned short* zr = zb + (size_t)grow * OUT_DIM + wn * 64 + cn0;
#pragma unroll
        for (int nf = 0; nf < 4; ++nf) {
            uint2 u;
            u.x = pack2f(acc[nf][0], acc[nf][1]);
            u.y = pack2f(acc[nf][2], acc[nf][3]);
            *(uint2*)(zr + nf * 16) = u;
        }
    }
}

// ---------------------------------------------------------------------------
// Decode: out[e] = sigmoid( sum_k z[a_e,k]*z[b_e,k]*w3[k] ), z in bf16.
// 16 lanes per edge, 4 edges/wave, grid-stride UNROLLED x2 (2x MLP).
// ---------------------------------------------------------------------------
__device__ inline float dotw3(const uint4& ua, const uint4& ub, const f32x2* w3v) {
    const unsigned pa[4] = {ua.x, ua.y, ua.z, ua.w};
    const unsigned pb[4] = {ub.x, ub.y, ub.z, ub.w};
    f32x2 vv = (f32x2){0.f, 0.f};
#pragma unroll
    for (int i = 0; i < 4; ++i) {
        f32x2 A = (f32x2){__uint_as_float(pa[i] << 16),
                          __uint_as_float(pa[i] & 0xFFFF0000u)};
        f32x2 B = (f32x2){__uint_as_float(pb[i] << 16),
                          __uint_as_float(pb[i] & 0xFFFF0000u)};
        vv += (A * B) * w3v[i];  // v_pk_mul_f32 + v_pk_fma_f32
    }
    return vv.x + vv.y;
}

__global__ __launch_bounds__(256) void decode_kernel(const unsigned short* __restrict__ zb,
                                                     const int* __restrict__ e1,
                                                     const int* __restrict__ e2,
                                                     const float* __restrict__ w3,
                                                     float* __restrict__ out,
                                                     int E1, int E2) {
    const int tid  = threadIdx.x;
    const int lane = tid & 63;
    const int sub  = lane & 15;   // lane within 16-group
    const int sg   = lane >> 4;   // edge slot within wave (0..3)
    const int Etot = E1 + E2;
    const int nq   = (Etot + 3) >> 2;

    f32x2 w3v[4];
    {
        const float4 wlo = *(const float4*)(w3 + sub * 8);
        const float4 whi = *(const float4*)(w3 + sub * 8 + 4);
        w3v[0] = (f32x2){wlo.x, wlo.y};
        w3v[1] = (f32x2){wlo.z, wlo.w};
        w3v[2] = (f32x2){whi.x, whi.y};
        w3v[3] = (f32x2){whi.z, whi.w};
    }

    const int wave = blockIdx.x * 4 + (tid >> 6);
    const int S    = gridDim.x * 4;  // stride in quads

    for (int q = wave; q < nq; q += 2 * S) {
        const int q2    = q + S;
        const bool has2 = (q2 < nq);

        const int e_a = q * 4 + sg;
        const int e_b = has2 ? (q2 * 4 + sg) : e_a;
        const int ca  = min(e_a, Etot - 1);
        const int cb  = min(e_b, Etot - 1);

        // both index loads up front
        const int2 ia = (ca < E1) ? ((const int2*)e1)[ca] : ((const int2*)e2)[ca - E1];
        const int2 ib = (cb < E1) ? ((const int2*)e1)[cb] : ((const int2*)e2)[cb - E1];

        // all 4 row gathers issued before any math
        const uint4 a1 = *(const uint4*)(zb + (size_t)ia.x * OUT_DIM + sub * 8);
        const uint4 b1 = *(const uint4*)(zb + (size_t)ia.y * OUT_DIM + sub * 8);
        const uint4 a2 = *(const uint4*)(zb + (size_t)ib.x * OUT_DIM + sub * 8);
        const uint4 b2 = *(const uint4*)(zb + (size_t)ib.y * OUT_DIM + sub * 8);

        float v1 = dotw3(a1, b1, w3v);
        float v2 = dotw3(a2, b2, w3v);

        v1 += __shfl_xor(v1, 8);  v2 += __shfl_xor(v2, 8);
        v1 += __shfl_xor(v1, 4);  v2 += __shfl_xor(v2, 4);
        v1 += __shfl_xor(v1, 2);  v2 += __shfl_xor(v2, 2);
        v1 += __shfl_xor(v1, 1);  v2 += __shfl_xor(v2, 1);

        if (sub == 0) {
            if (e_a < Etot) out[e_a] = 1.f / (1.f + __expf(-v1));
            if (has2 && e_b < Etot) out[e_b] = 1.f / (1.f + __expf(-v2));
        }
    }
}

extern "C" void kernel_launch(void* const* d_in, const int* in_sizes, int n_in,
                              void* d_out, int out_size, void* d_ws, size_t ws_size,
                              hipStream_t stream) {
    const float* x  = (const float*)d_in[0];
    const int*   e1 = (const int*)d_in[1];
    const int*   e2 = (const int*)d_in[2];
    const float* w  = (const float*)d_in[3];
    const float* w3 = (const float*)d_in[4];

    float* out = (float*)d_out;

    const int M  = in_sizes[0] / IN_DIM;  // 100000
    const int E1 = in_sizes[1] / 2;       // 300000
    const int E2 = in_sizes[2] / 2;       // 300000

    // workspace: z_bf [M,128] bf16 (25.6 MB), then wt2 [512x128] bf16 (128 KB)
    unsigned short* zbuf = (unsigned short*)d_ws;
    unsigned short* wt2  = zbuf + (size_t)M * OUT_DIM;

    wt2_kernel<<<(IN_DIM * OUT_DIM) / 256, 256, 0, stream>>>(w, wt2);
    gemm_mfma<<<(M + BM - 1) / BM, 512, 0, stream>>>(x, wt2, zbuf, M);
    decode_kernel<<<2048, 256, 0, stream>>>(zbuf, e1, e2, w3, out, E1, E2);
}

// Round 15
// 88.762 us; speedup vs baseline: 2.0128x; 2.0128x over previous
//
#include <hip/hip_runtime.h>
#include <math.h>

#define IN_DIM 512
#define OUT_DIM 128
#define BM 64
#define BK 64
#define NKT (IN_DIM / BK)  // 8

typedef __attribute__((ext_vector_type(8))) __bf16 bf16x8;
typedef __attribute__((ext_vector_type(2))) __bf16 bf16x2;
typedef __attribute__((ext_vector_type(4))) float f32x4;
typedef __attribute__((ext_vector_type(2))) float f32x2;

// Manual RNE fp32->bf16 (bit ops) — r5-proven codegen for epilogue/prep.
__device__ inline unsigned short f2bf(float f) {
    unsigned u = __float_as_uint(f);
    u += 0x7FFFu + ((u >> 16) & 1u);  // round-to-nearest-even
    return (unsigned short)(u >> 16);
}
__device__ inline unsigned pack2f(float a, float b) {
    return (unsigned)f2bf(a) | ((unsigned)f2bf(b) << 16);
}

// In-register fp32x8 -> bf16x8 via native paired casts, consumed immediately.
__device__ inline bf16x8 cvt8(const f32x4& lo, const f32x4& hi) {
    bf16x2 p0 = {(__bf16)lo.x, (__bf16)lo.y};
    bf16x2 p1 = {(__bf16)lo.z, (__bf16)lo.w};
    bf16x2 p2 = {(__bf16)hi.x, (__bf16)hi.y};
    bf16x2 p3 = {(__bf16)hi.z, (__bf16)hi.w};
    uint4 u = {__builtin_bit_cast(unsigned, p0), __builtin_bit_cast(unsigned, p1),
               __builtin_bit_cast(unsigned, p2), __builtin_bit_cast(unsigned, p3)};
    return __builtin_bit_cast(bf16x8, u);
}

// async global->LDS, 16B per lane (dest = wave-uniform base + lane*16)
__device__ inline void gload_lds16(const void* g, void* l) {
    __builtin_amdgcn_global_load_lds(
        (const __attribute__((address_space(1))) void*)g,
        (__attribute__((address_space(3))) void*)l, 16, 0, 0);
}

// w [512][128] f32 -> wt2 k-interleaved bf16: wt2[(k>>3)*128 + n][k&7]
__global__ void wt2_kernel(const float* __restrict__ w, unsigned short* __restrict__ wt2) {
    int idx = blockIdx.x * 256 + threadIdx.x;  // 65536 total
    int k = idx >> 7;
    int n = idx & 127;
    wt2[(((k >> 3) * 128) + n) * 8 + (k & 7)] = f2bf(w[idx]);
}

// ---------------------------------------------------------------------------
// z_bf[M,128](bf16) = x[M,512] @ w[512,128] via bf16 MFMA, fp32 accumulate.
// r10 champion structure (DMA double-buffered A, 2-phase, drain barrier) +
// FIFO-correct register-prefetched B:
//   phase t: [Bk1(t) loads — OLDEST] sched_barrier
//            [Bk0(t+1) prefetch][DMA(t+1)] — youngest
//            [ds_read+cvt A(t)][MFMA ks0 w/ Bk0 regs (no wait)]
//            [MFMA ks1 w/ Bk1(t) — waits only on its own 4 loads]
//            __syncthreads (vmcnt0 drain: B(t+1)+DMA(t+1) had full phase)
// Swapped-operand MFMA -> packed uint2 epilogue (r13-validated).
// 4 waves (2x2), wave = 32x64 out. LDS 32 KB -> 4 blocks/CU at bounds(256,4).
// ---------------------------------------------------------------------------
__global__ __launch_bounds__(256, 4) void gemm_mfma(const float* __restrict__ x,
                                                    const unsigned short* __restrict__ wt2,
                                                    unsigned short* __restrict__ zb,
                                                    int M) {
    __shared__ float sA[2][BM * BK];  // 2 x 16 KB fp32, col-swizzled
    char* const pAb = (char*)sA;

    const int tid  = threadIdx.x;
    const int lane = tid & 63;
    const int wid  = tid >> 6;
    const int wm   = wid >> 1;  // 0..1
    const int wn   = wid & 1;   // 0..1
    const int block_row = blockIdx.x * BM;

    const int fr  = lane & 15;  // fragment row (A=m) / col (B=n)
    const int fk4 = lane >> 4;  // k-octet group 0..3

    f32x4 acc[2][4];
#pragma unroll
    for (int i = 0; i < 2; ++i)
#pragma unroll
        for (int j = 0; j < 4; ++j) acc[i][j] = (f32x4){0.f, 0.f, 0.f, 0.f};

    // staging map (r10-validated): chunk c = wid*4+i covers LDS [c*1024,+1024)
    // = rows 4c..4c+3 (256 B/row). Lane: row 4c+(lane>>4), bytes (lane&15)*16.
    const int s_row = lane >> 4;
    const int s_cb  = (lane & 15) * 16;

    // fragment-read map (logical row, swizzled column)
    const int rowa0 = wm * 32 + fr;
    const int rowa1 = rowa0 + 16;
    const int swz7  = (fr & 7) << 5;

    // B per-lane base in wt2 (element units)
    const unsigned short* pb = wt2 + fk4 * 1024 + (wn * 64 + fr) * 8;

    // named B register buffers (rule #20)
    bf16x8 Ba0, Ba1, Ba2, Ba3;  // ks0, even tiles
    bf16x8 Bb0, Bb1, Bb2, Bb3;  // ks0, odd tiles
    bf16x8 K10, K11, K12, K13;  // ks1, current tile

#define LOADB0(T, R0, R1, R2, R3)                         \
    R0 = *(const bf16x8*)(pb + (T) * 8192 + 0);           \
    R1 = *(const bf16x8*)(pb + (T) * 8192 + 128);         \
    R2 = *(const bf16x8*)(pb + (T) * 8192 + 256);         \
    R3 = *(const bf16x8*)(pb + (T) * 8192 + 384);

#define LOADB1(T)                                         \
    K10 = *(const bf16x8*)(pb + (T) * 8192 + 4096 + 0);   \
    K11 = *(const bf16x8*)(pb + (T) * 8192 + 4096 + 128); \
    K12 = *(const bf16x8*)(pb + (T) * 8192 + 4096 + 256); \
    K13 = *(const bf16x8*)(pb + (T) * 8192 + 4096 + 384);

#define STAGE(T, BUF)                                                            \
    {                                                                            \
        _Pragma("unroll") for (int i = 0; i < 4; ++i) {                          \
            const int rr = (wid * 4 + i) * 4 + s_row;                            \
            int grow = block_row + rr;                                           \
            grow = (grow < M) ? grow : (M - 1);                                  \
            const char* src = (const char*)x + (size_t)grow * 2048 +             \
                              (T) * 256 + (s_cb ^ ((rr & 7) << 5));              \
            gload_lds16(src, pAb + (BUF) * 16384 + (wid * 4 + i) * 1024);        \
        }                                                                        \
    }

#define COMP(BUF, B0, B1, B2, B3)                                                \
    {                                                                            \
        const char* pT = pAb + (BUF) * 16384;                                    \
        /* ks = 0 : B from regs (loaded last phase), zero VMEM wait */           \
        {                                                                        \
            const int cb = (fk4 * 32) ^ swz7;                                    \
            f32x4 lo0 = *(const f32x4*)(pT + rowa0 * 256 + cb);                  \
            f32x4 hi0 = *(const f32x4*)(pT + rowa0 * 256 + cb + 16);             \
            f32x4 lo1 = *(const f32x4*)(pT + rowa1 * 256 + cb);                  \
            f32x4 hi1 = *(const f32x4*)(pT + rowa1 * 256 + cb + 16);             \
            bf16x8 af0 = cvt8(lo0, hi0);                                         \
            bf16x8 af1 = cvt8(lo1, hi1);                                         \
            acc[0][0] = __builtin_amdgcn_mfma_f32_16x16x32_bf16(B0, af0, acc[0][0], 0, 0, 0); \
            acc[0][1] = __builtin_amdgcn_mfma_f32_16x16x32_bf16(B1, af0, acc[0][1], 0, 0, 0); \
            acc[0][2] = __builtin_amdgcn_mfma_f32_16x16x32_bf16(B2, af0, acc[0][2], 0, 0, 0); \
            acc[0][3] = __builtin_amdgcn_mfma_f32_16x16x32_bf16(B3, af0, acc[0][3], 0, 0, 0); \
            acc[1][0] = __builtin_amdgcn_mfma_f32_16x16x32_bf16(B0, af1, acc[1][0], 0, 0, 0); \
            acc[1][1] = __builtin_amdgcn_mfma_f32_16x16x32_bf16(B1, af1, acc[1][1], 0, 0, 0); \
            acc[1][2] = __builtin_amdgcn_mfma_f32_16x16x32_bf16(B2, af1, acc[1][2], 0, 0, 0); \
            acc[1][3] = __builtin_amdgcn_mfma_f32_16x16x32_bf16(B3, af1, acc[1][3], 0, 0, 0); \
        }                                                                        \
        /* ks = 1 : B = K1x regs loaded FIRST this phase (oldest VMEM) */        \
        {                                                                        \
            const int cb = (128 + fk4 * 32) ^ swz7;                              \
            f32x4 lo0 = *(const f32x4*)(pT + rowa0 * 256 + cb);                  \
            f32x4 hi0 = *(const f32x4*)(pT + rowa0 * 256 + cb + 16);             \
            f32x4 lo1 = *(const f32x4*)(pT + rowa1 * 256 + cb);                  \
            f32x4 hi1 = *(const f32x4*)(pT + rowa1 * 256 + cb + 16);             \
            bf16x8 af0 = cvt8(lo0, hi0);                                         \
            bf16x8 af1 = cvt8(lo1, hi1);                                         \
            acc[0][0] = __builtin_amdgcn_mfma_f32_16x16x32_bf16(K10, af0, acc[0][0], 0, 0, 0); \
            acc[0][1] = __builtin_amdgcn_mfma_f32_16x16x32_bf16(K11, af0, acc[0][1], 0, 0, 0); \
            acc[0][2] = __builtin_amdgcn_mfma_f32_16x16x32_bf16(K12, af0, acc[0][2], 0, 0, 0); \
            acc[0][3] = __builtin_amdgcn_mfma_f32_16x16x32_bf16(K13, af0, acc[0][3], 0, 0, 0); \
            acc[1][0] = __builtin_amdgcn_mfma_f32_16x16x32_bf16(K10, af1, acc[1][0], 0, 0, 0); \
            acc[1][1] = __builtin_amdgcn_mfma_f32_16x16x32_bf16(K11, af1, acc[1][1], 0, 0, 0); \
            acc[1][2] = __builtin_amdgcn_mfma_f32_16x16x32_bf16(K12, af1, acc[1][2], 0, 0, 0); \
            acc[1][3] = __builtin_amdgcn_mfma_f32_16x16x32_bf16(K13, af1, acc[1][3], 0, 0, 0); \
        }                                                                        \
    }

#define SB __builtin_amdgcn_sched_barrier(0);

    // prologue: stage tile 0 + prefetch its ks0 B regs, drain
    STAGE(0, 0);
    LOADB0(0, Ba0, Ba1, Ba2, Ba3);
    __syncthreads();

    // 8 phases, buf = t&1, ks0-B alternates Ba (even) / Bb (odd)
    LOADB1(0); SB; LOADB0(1, Bb0, Bb1, Bb2, Bb3); STAGE(1, 1);
    COMP(0, Ba0, Ba1, Ba2, Ba3); __syncthreads();

    LOADB1(1); SB; LOADB0(2, Ba0, Ba1, Ba2, Ba3); STAGE(2, 0);
    COMP(1, Bb0, Bb1, Bb2, Bb3); __syncthreads();

    LOADB1(2); SB; LOADB0(3, Bb0, Bb1, Bb2, Bb3); STAGE(3, 1);
    COMP(0, Ba0, Ba1, Ba2, Ba3); __syncthreads();

    LOADB1(3); SB; LOADB0(4, Ba0, Ba1, Ba2, Ba3); STAGE(4, 0);
    COMP(1, Bb0, Bb1, Bb2, Bb3); __syncthreads();

    LOADB1(4); SB; LOADB0(5, Bb0, Bb1, Bb2, Bb3); STAGE(5, 1);
    COMP(0, Ba0, Ba1, Ba2, Ba3); __syncthreads();

    LOADB1(5); SB; LOADB0(6, Ba0, Ba1, Ba2, Ba3); STAGE(6, 0);
    COMP(1, Bb0, Bb1, Bb2, Bb3); __syncthreads();

    LOADB1(6); SB; LOADB0(7, Bb0, Bb1, Bb2, Bb3); STAGE(7, 1);
    COMP(0, Ba0, Ba1, Ba2, Ba3); __syncthreads();

    LOADB1(7); SB;
    COMP(1, Bb0, Bb1, Bb2, Bb3);

#undef LOADB0
#undef LOADB1
#undef STAGE
#undef COMP
#undef SB

    // Swapped C/D layout: col=lane&15 -> m, rows -> n. Packed 8-B stores.
    const int cm  = lane & 15;
    const int cn0 = (lane >> 4) * 4;
#pragma unroll
    for (int mf = 0; mf < 2; ++mf) {
        const int grow = block_row + wm * 32 + mf * 16 + cm;
        if (grow < M) {
            unsigned short* zr = zb + (size_t)grow * OUT_DIM + wn * 64 + cn0;
#pragma unroll
            for (int nf = 0; nf < 4; ++nf) {
                uint2 u;
                u.x = pack2f(acc[mf][nf][0], acc[mf][nf][1]);
                u.y = pack2f(acc[mf][nf][2], acc[mf][nf][3]);
                *(uint2*)(zr + nf * 16) = u;
            }
        }
    }
}

// ---------------------------------------------------------------------------
// Decode: out[e] = sigmoid( sum_k z[a_e,k]*z[b_e,k]*w3[k] ), z in bf16.
// 16 lanes per edge, 4 edges/wave, grid-stride UNROLLED x2 (2x MLP).
// ---------------------------------------------------------------------------
__device__ inline float dotw3(const uint4& ua, const uint4& ub, const f32x2* w3v) {
    const unsigned pa[4] = {ua.x, ua.y, ua.z, ua.w};
    const unsigned pb[4] = {ub.x, ub.y, ub.z, ub.w};
    f32x2 vv = (f32x2){0.f, 0.f};
#pragma unroll
    for (int i = 0; i < 4; ++i) {
        f32x2 A = (f32x2){__uint_as_float(pa[i] << 16),
                          __uint_as_float(pa[i] & 0xFFFF0000u)};
        f32x2 B = (f32x2){__uint_as_float(pb[i] << 16),
                          __uint_as_float(pb[i] & 0xFFFF0000u)};
        vv += (A * B) * w3v[i];  // v_pk_mul_f32 + v_pk_fma_f32
    }
    return vv.x + vv.y;
}

__global__ __launch_bounds__(256) void decode_kernel(const unsigned short* __restrict__ zb,
                                                     const int* __restrict__ e1,
                                                     const int* __restrict__ e2,
                                                     const float* __restrict__ w3,
                                                     float* __restrict__ out,
                                                     int E1, int E2) {
    const int tid  = threadIdx.x;
    const int lane = tid & 63;
    const int sub  = lane & 15;   // lane within 16-group
    const int sg   = lane >> 4;   // edge slot within wave (0..3)
    const int Etot = E1 + E2;
    const int nq   = (Etot + 3) >> 2;

    f32x2 w3v[4];
    {
        const float4 wlo = *(const float4*)(w3 + sub * 8);
        const float4 whi = *(const float4*)(w3 + sub * 8 + 4);
        w3v[0] = (f32x2){wlo.x, wlo.y};
        w3v[1] = (f32x2){wlo.z, wlo.w};
        w3v[2] = (f32x2){whi.x, whi.y};
        w3v[3] = (f32x2){whi.z, whi.w};
    }

    const int wave = blockIdx.x * 4 + (tid >> 6);
    const int S    = gridDim.x * 4;  // stride in quads

    for (int q = wave; q < nq; q += 2 * S) {
        const int q2    = q + S;
        const bool has2 = (q2 < nq);

        const int e_a = q * 4 + sg;
        const int e_b = has2 ? (q2 * 4 + sg) : e_a;
        const int ca  = min(e_a, Etot - 1);
        const int cb  = min(e_b, Etot - 1);

        // both index loads up front
        const int2 ia = (ca < E1) ? ((const int2*)e1)[ca] : ((const int2*)e2)[ca - E1];
        const int2 ib = (cb < E1) ? ((const int2*)e1)[cb] : ((const int2*)e2)[cb - E1];

        // all 4 row gathers issued before any math
        const uint4 a1 = *(const uint4*)(zb + (size_t)ia.x * OUT_DIM + sub * 8);
        const uint4 b1 = *(const uint4*)(zb + (size_t)ia.y * OUT_DIM + sub * 8);
        const uint4 a2 = *(const uint4*)(zb + (size_t)ib.x * OUT_DIM + sub * 8);
        const uint4 b2 = *(const uint4*)(zb + (size_t)ib.y * OUT_DIM + sub * 8);

        float v1 = dotw3(a1, b1, w3v);
        float v2 = dotw3(a2, b2, w3v);

        v1 += __shfl_xor(v1, 8);  v2 += __shfl_xor(v2, 8);
        v1 += __shfl_xor(v1, 4);  v2 += __shfl_xor(v2, 4);
        v1 += __shfl_xor(v1, 2);  v2 += __shfl_xor(v2, 2);
        v1 += __shfl_xor(v1, 1);  v2 += __shfl_xor(v2, 1);

        if (sub == 0) {
            if (e_a < Etot) out[e_a] = 1.f / (1.f + __expf(-v1));
            if (has2 && e_b < Etot) out[e_b] = 1.f / (1.f + __expf(-v2));
        }
    }
}

extern "C" void kernel_launch(void* const* d_in, const int* in_sizes, int n_in,
                              void* d_out, int out_size, void* d_ws, size_t ws_size,
                              hipStream_t stream) {
    const float* x  = (const float*)d_in[0];
    const int*   e1 = (const int*)d_in[1];
    const int*   e2 = (const int*)d_in[2];
    const float* w  = (const float*)d_in[3];
    const float* w3 = (const float*)d_in[4];

    float* out = (float*)d_out;

    const int M  = in_sizes[0] / IN_DIM;  // 100000
    const int E1 = in_sizes[1] / 2;       // 300000
    const int E2 = in_sizes[2] / 2;       // 300000

    // workspace: z_bf [M,128] bf16 (25.6 MB), then wt2 [512x128] bf16 (128 KB)
    unsigned short* zbuf = (unsigned short*)d_ws;
    unsigned short* wt2  = zbuf + (size_t)M * OUT_DIM;

    wt2_kernel<<<(IN_DIM * OUT_DIM) / 256, 256, 0, stream>>>(w, wt2);
    gemm_mfma<<<(M + BM - 1) / BM, 256, 0, stream>>>(x, wt2, zbuf, M);
    decode_kernel<<<2048, 256, 0, stream>>>(zbuf, e1, e2, w3, out, E1, E2);
}